// Round 8
// baseline (465.501 us; speedup 1.0000x reference)
//
#include <hip/hip_runtime.h>

// ---------------------------------------------------------------------------
// LiteMLA: B=4, N=4096, C=1024, D=32, h=32 heads.
//   qkv = x @ W_qkv^T            (16384 x 3072, K=1024)   [relu on q,k cols]
//   per (b,h): vk[d,e] = sum_n Vpad[d,n]*reluK[e,n]   (33x32, reduce N=4096)
//              y[d,n]  = (sum_e vk[d,e]*reluQ[e,n]) / (sum_e vk[32,e]*reluQ[e,n] + eps)
//   out = y @ W_proj^T + b_proj  (16384 x 1024, K=1024)
// gemm_qkv stores Q token-major and K/V transposed (kvT[b][ch][n]).
// attn_tail = vk + apply + proj in ONE persistent kernel (512 blocks,
// 2 blocks/CU guaranteed) with manual device-scope grid barriers -> removes
// two inter-dispatch seams.
// ---------------------------------------------------------------------------

using us8   = __attribute__((ext_vector_type(8))) unsigned short;
using us4   = __attribute__((ext_vector_type(4))) unsigned short;
using s8v   = __attribute__((ext_vector_type(8))) short;
using f32x4 = __attribute__((ext_vector_type(4))) float;

__device__ __forceinline__ unsigned short f2bf(float f) {
    union { float f; unsigned int u; } c; c.f = f;
    unsigned int r = c.u + 0x7fffu + ((c.u >> 16) & 1u);   // RTN-even
    return (unsigned short)(r >> 16);
}
__device__ __forceinline__ float bf2f(unsigned short u) {
    union { unsigned int u; float f; } c; c.u = ((unsigned int)u) << 16;
    return c.f;
}

// async global->LDS, 16B per lane; LDS dest = wave-uniform base + lane*16
__device__ __forceinline__ void async16(const unsigned short* g, unsigned short* l) {
    __builtin_amdgcn_global_load_lds(
        (const __attribute__((address_space(1))) unsigned int*)g,
        (__attribute__((address_space(3))) unsigned int*)l, 16, 0, 0);
}

// device-scope grid barrier: monotone counter, one arrive per block.
__device__ __forceinline__ void grid_barrier(unsigned* cnt, unsigned target) {
    __syncthreads();
    if (threadIdx.x == 0) {
        __threadfence();                       // publish my writes
        atomicAdd(cnt, 1u);
        while (atomicAdd(cnt, 0u) < target) {} // device-scope poll
        __threadfence();
    }
    __syncthreads();
}

// ------------------ fused fp32->bf16 converts + vkws/cnt zero --------------
__global__ __launch_bounds__(256)
void prep(const float* __restrict__ x, const float* __restrict__ wq,
          const float* __restrict__ wp, unsigned short* __restrict__ xb,
          unsigned short* __restrict__ wqb, unsigned short* __restrict__ wpb,
          float* __restrict__ vkws) {
    const int NX = 16777216 / 8, NQ = 3145728 / 8, NP = 1048576 / 8;
    const int NZ = (135168 + 16) / 8;          // vkws + barrier counter
    int gid = blockIdx.x * 256 + threadIdx.x;
    const float* in; unsigned short* out; int i;
    if (gid < NX)                    { in = x;  out = xb;  i = gid * 8; }
    else if (gid < NX + NQ)          { in = wq; out = wqb; i = (gid - NX) * 8; }
    else if (gid < NX + NQ + NP)     { in = wp; out = wpb; i = (gid - NX - NQ) * 8; }
    else if (gid < NX + NQ + NP + NZ) {
        int z = (gid - NX - NQ - NP) * 8;
        f32x4 zero = {};
        *(f32x4*)(vkws + z) = zero; *(f32x4*)(vkws + z + 4) = zero;
        return;
    } else return;
    float4 a = *(const float4*)(in + i);
    float4 b = *(const float4*)(in + i + 4);
    us8 o;
    o[0] = f2bf(a.x); o[1] = f2bf(a.y); o[2] = f2bf(a.z); o[3] = f2bf(a.w);
    o[4] = f2bf(b.x); o[5] = f2bf(b.y); o[6] = f2bf(b.z); o[7] = f2bf(b.w);
    *(us8*)(out + i) = o;
}

// ----------------------------- gemm_qkv ------------------------------------
// C[m,n] = sum_k A[m,k]*Bt[n,k].  128x128 tile, BK=64 (two 32-panels),
// 256 threads (4 waves).  XOR k-octet LDS swizzle (bank-conflict-free).
// cols<1024 -> Q token-major bf16 (relu); cols>=1024 -> kvT transposed bf16.
__global__ __launch_bounds__(256)
void gemm_qkv(const unsigned short* __restrict__ A,
              const unsigned short* __restrict__ Bt,
              unsigned short* __restrict__ Cq, unsigned short* __restrict__ kvT,
              int M, int N, int K) {
    __shared__ unsigned short As0[128 * 32], As1[128 * 32];
    __shared__ unsigned short Bs0[128 * 32], Bs1[128 * 32];

    const int tid  = threadIdx.x;
    const int lane = tid & 63;
    const int wv   = tid >> 6;
    const int wr   = wv >> 1, wc = wv & 1;

    const int MT  = M >> 7;
    const int bpg = MT * 8;
    const int g   = blockIdx.x / bpg;
    const int r   = blockIdx.x % bpg;
    const int tM  = (r >> 3) * 128;
    const int tN  = (g * 8 + (r & 7)) * 128;

    f32x4 acc[4][4] = {};

    const int sseg = ((lane & 3) ^ ((lane >> 3) & 3)) * 8;
    const unsigned short* Ag = A + (size_t)(tM + wv * 32 + (lane >> 2)) * K + sseg;
    const unsigned short* Bg = Bt + (size_t)(tN + wv * 32 + (lane >> 2)) * K + sseg;
    const int wo = wv * 32 * 32;

    const int mrow = lane & 15;
    const int kqx  = (((lane >> 4) ^ ((lane >> 1) & 3))) * 8;

    for (int k0 = 0; k0 < K; k0 += 64) {
        __syncthreads();
        async16(Ag + k0,               &As0[wo]);
        async16(Ag + k0 + 16 * K,      &As0[wo + 16 * 32]);
        async16(Ag + k0 + 32,          &As1[wo]);
        async16(Ag + k0 + 32 + 16 * K, &As1[wo + 16 * 32]);
        async16(Bg + k0,               &Bs0[wo]);
        async16(Bg + k0 + 16 * K,      &Bs0[wo + 16 * 32]);
        async16(Bg + k0 + 32,          &Bs1[wo]);
        async16(Bg + k0 + 32 + 16 * K, &Bs1[wo + 16 * 32]);
        asm volatile("s_waitcnt vmcnt(0)" ::: "memory");
        __syncthreads();
        s8v af[4], bf[4];
#pragma unroll
        for (int mi = 0; mi < 4; ++mi)
            af[mi] = *(const s8v*)&As0[(wr * 64 + mi * 16 + mrow) * 32 + kqx];
#pragma unroll
        for (int ni = 0; ni < 4; ++ni)
            bf[ni] = *(const s8v*)&Bs0[(wc * 64 + ni * 16 + mrow) * 32 + kqx];
#pragma unroll
        for (int mi = 0; mi < 4; ++mi)
#pragma unroll
            for (int ni = 0; ni < 4; ++ni)
                acc[mi][ni] = __builtin_amdgcn_mfma_f32_16x16x32_bf16(
                    af[mi], bf[ni], acc[mi][ni], 0, 0, 0);
#pragma unroll
        for (int mi = 0; mi < 4; ++mi)
            af[mi] = *(const s8v*)&As1[(wr * 64 + mi * 16 + mrow) * 32 + kqx];
#pragma unroll
        for (int ni = 0; ni < 4; ++ni)
            bf[ni] = *(const s8v*)&Bs1[(wc * 64 + ni * 16 + mrow) * 32 + kqx];
#pragma unroll
        for (int mi = 0; mi < 4; ++mi)
#pragma unroll
            for (int ni = 0; ni < 4; ++ni)
                acc[mi][ni] = __builtin_amdgcn_mfma_f32_16x16x32_bf16(
                    af[mi], bf[ni], acc[mi][ni], 0, 0, 0);
    }

    const int crow0 = (lane >> 4) * 4;
    const int ccol  = lane & 15;
    if (tN >= 1024) {
        const int b2 = tM >> 12;
        const int nb0 = (tM & 4095) + wr * 64;
#pragma unroll
        for (int mi = 0; mi < 4; ++mi) {
            int nbase = nb0 + mi * 16 + crow0;
#pragma unroll
            for (int ni = 0; ni < 4; ++ni) {
                int col = tN + wc * 64 + ni * 16 + ccol;
                f32x4 v = acc[mi][ni];
                if (col < 2048) {
                    v[0] = fmaxf(v[0], 0.f); v[1] = fmaxf(v[1], 0.f);
                    v[2] = fmaxf(v[2], 0.f); v[3] = fmaxf(v[3], 0.f);
                }
                us4 o;
                o[0] = f2bf(v[0]); o[1] = f2bf(v[1]);
                o[2] = f2bf(v[2]); o[3] = f2bf(v[3]);
                *(us4*)&kvT[((size_t)b2 * 2048 + (col - 1024)) * 4096 + nbase] = o;
            }
        }
    } else {
#pragma unroll
        for (int mi = 0; mi < 4; ++mi)
#pragma unroll
            for (int ni = 0; ni < 4; ++ni) {
                int row = tM + wr * 64 + mi * 16 + crow0;
                int col = tN + wc * 64 + ni * 16 + ccol;
#pragma unroll
                for (int r2 = 0; r2 < 4; ++r2) {
                    float v = fmaxf(acc[mi][ni][r2], 0.f);
                    Cq[(size_t)(row + r2) * 1024 + col] = f2bf(v);
                }
            }
    }
}

// --------------------------- attn_tail (fused) -----------------------------
// 512 blocks x 256 thr, >=2 blocks/CU guaranteed -> all co-resident.
// Phase 1: vk partials (2 units/blk)  -> grid barrier(512)
// Phase 2: apply       (4 units/blk)  -> grid barrier(1024)
// Phase 3: proj GEMM   (2 tiles/blk)
__global__ __launch_bounds__(256, 2)
void attn_tail(const unsigned short* __restrict__ kvT,
               const unsigned short* __restrict__ qb,
               unsigned short* __restrict__ ybuf,
               const unsigned short* __restrict__ wprojb,
               const float* __restrict__ bias,
               float* __restrict__ out,
               float* __restrict__ vkws, unsigned* cnt) {
    __shared__ char lds[34816];
    const int blk = blockIdx.x, t = threadIdx.x;
    const int lane = t & 63, wv = t >> 6;

    // ------------------------- phase 1: vk --------------------------------
    {
        const int S = 136;
        unsigned short* Ks = (unsigned short*)lds;            // 8704 B
        unsigned short* Vs = (unsigned short*)(lds + 8704);   // 8704 B
        float* Rsb = (float*)(lds + 17408);                   // 4*1088*4 B
        const int sr = t >> 3, ss = (t & 7) * 16;
        const int mrow = lane & 15, kq = (lane >> 4) * 8;
        s8v ones;
#pragma unroll
        for (int j2 = 0; j2 < 8; ++j2) ones[j2] = (short)0x3F80;

        for (int j = 0; j < 2; ++j) {
            const int u = blk * 2 + j;
            const int bh = u >> 3, ck = u & 7;
            const int b = bh >> 5, h = bh & 31;
            const unsigned short* Kp = kvT + ((size_t)b * 2048 + h * 32) * 4096 + ck * 512;
            const unsigned short* Vp = kvT + ((size_t)b * 2048 + 1024 + h * 32) * 4096 + ck * 512;
            f32x4 a00 = {}, a01 = {}, a10 = {}, a11 = {}, aO0 = {}, aO1 = {};
            for (int tile = 0; tile < 4; ++tile) {
                int go = tile * 128 + ss;
                us8 k0v = *(const us8*)(Kp + (size_t)sr * 4096 + go);
                us8 k1v = *(const us8*)(Kp + (size_t)sr * 4096 + go + 8);
                us8 v0v = *(const us8*)(Vp + (size_t)sr * 4096 + go);
                us8 v1v = *(const us8*)(Vp + (size_t)sr * 4096 + go + 8);
                __syncthreads();
                *(us8*)&Ks[sr * S + ss]     = k0v;
                *(us8*)&Ks[sr * S + ss + 8] = k1v;
                *(us8*)&Vs[sr * S + ss]     = v0v;
                *(us8*)&Vs[sr * S + ss + 8] = v1v;
                __syncthreads();
                int ko = wv * 32 + kq;
                s8v a0 = *(const s8v*)&Vs[(mrow)      * S + ko];
                s8v a1 = *(const s8v*)&Vs[(16 + mrow) * S + ko];
                s8v b0 = *(const s8v*)&Ks[(mrow)      * S + ko];
                s8v b1 = *(const s8v*)&Ks[(16 + mrow) * S + ko];
                a00 = __builtin_amdgcn_mfma_f32_16x16x32_bf16(a0, b0, a00, 0, 0, 0);
                a01 = __builtin_amdgcn_mfma_f32_16x16x32_bf16(a0, b1, a01, 0, 0, 0);
                a10 = __builtin_amdgcn_mfma_f32_16x16x32_bf16(a1, b0, a10, 0, 0, 0);
                a11 = __builtin_amdgcn_mfma_f32_16x16x32_bf16(a1, b1, a11, 0, 0, 0);
                aO0 = __builtin_amdgcn_mfma_f32_16x16x32_bf16(ones, b0, aO0, 0, 0, 0);
                aO1 = __builtin_amdgcn_mfma_f32_16x16x32_bf16(ones, b1, aO1, 0, 0, 0);
            }
            const int ccol = lane & 15, crow = (lane >> 4) * 4;
            float* R = Rsb + wv * 1088;
#pragma unroll
            for (int r2 = 0; r2 < 4; ++r2) {
                R[(crow + r2) * 32 + ccol]           = a00[r2];
                R[(crow + r2) * 32 + 16 + ccol]      = a01[r2];
                R[(16 + crow + r2) * 32 + ccol]      = a10[r2];
                R[(16 + crow + r2) * 32 + 16 + ccol] = a11[r2];
            }
            if ((lane >> 4) == 0) {
                R[1024 + ccol]      = aO0[0];
                R[1024 + 16 + ccol] = aO1[0];
            }
            __syncthreads();
            float* vkb = vkws + bh * (33 * 32);
            for (int i = t; i < 1056; i += 256) {
                float s = Rsb[i] + Rsb[1088 + i] + Rsb[2176 + i] + Rsb[3264 + i];
                atomicAdd(&vkb[i], s);
            }
            __syncthreads();
        }
    }
    grid_barrier(cnt, 512);

    // ------------------------ phase 2: apply ------------------------------
    {
        unsigned short* vkh = (unsigned short*)lds;           // 3072 B
        unsigned short* vkl = (unsigned short*)(lds + 3072);  // 3072 B
        const int col = lane & 15, quad = lane >> 4;
        for (int j = 0; j < 4; ++j) {
            const int u = blk * 4 + j;
            const int bh = u >> 4, nb = u & 15;
            const int b = bh >> 5, h = bh & 31;
            for (int i = t; i < 48 * 32; i += 256) {
                float v = (i < 33 * 32) ? vkws[bh * (33 * 32) + i] : 0.f;
                unsigned short hi = f2bf(v);
                vkh[i] = hi;
                vkl[i] = f2bf(v - bf2f(hi));
            }
            __syncthreads();
            s8v b0h = *(const s8v*)&vkh[(col)      * 32 + quad * 8];
            s8v b0l = *(const s8v*)&vkl[(col)      * 32 + quad * 8];
            s8v b1h = *(const s8v*)&vkh[(16 + col) * 32 + quad * 8];
            s8v b1l = *(const s8v*)&vkl[(16 + col) * 32 + quad * 8];
            s8v b2h = *(const s8v*)&vkh[(32 + col) * 32 + quad * 8];
            s8v b2l = *(const s8v*)&vkl[(32 + col) * 32 + quad * 8];
            const int ntile = nb * 256 + wv * 64;
#pragma unroll
            for (int mi = 0; mi < 4; ++mi) {
                int tok = ntile + mi * 16 + col;
                const unsigned short* qp =
                    qb + (size_t)(b * 4096 + tok) * 1024 + h * 32 + quad * 8;
                s8v a = *(const s8v*)qp;
                f32x4 n0 = {}, n1 = {}, dd = {};
                n0 = __builtin_amdgcn_mfma_f32_16x16x32_bf16(b0h, a, n0, 0, 0, 0);
                n0 = __builtin_amdgcn_mfma_f32_16x16x32_bf16(b0l, a, n0, 0, 0, 0);
                n1 = __builtin_amdgcn_mfma_f32_16x16x32_bf16(b1h, a, n1, 0, 0, 0);
                n1 = __builtin_amdgcn_mfma_f32_16x16x32_bf16(b1l, a, n1, 0, 0, 0);
                dd = __builtin_amdgcn_mfma_f32_16x16x32_bf16(b2h, a, dd, 0, 0, 0);
                dd = __builtin_amdgcn_mfma_f32_16x16x32_bf16(b2l, a, dd, 0, 0, 0);
                float den  = __shfl(dd[0], col, 64);
                float rinv = 1.f / (den + 1e-15f);
                us4 o0, o1;
#pragma unroll
                for (int r2 = 0; r2 < 4; ++r2) {
                    o0[r2] = f2bf(n0[r2] * rinv);
                    o1[r2] = f2bf(n1[r2] * rinv);
                }
                size_t o = (size_t)(b * 4096 + tok) * 1024 + h * 32;
                *(us4*)&ybuf[o + quad * 4]      = o0;
                *(us4*)&ybuf[o + 16 + quad * 4] = o1;
            }
            __syncthreads();
        }
    }
    grid_barrier(cnt, 1024);

    // ------------------------- phase 3: proj ------------------------------
    {
        unsigned short* As0 = (unsigned short*)lds;             // 8192 B each
        unsigned short* As1 = (unsigned short*)(lds + 8192);
        unsigned short* Bs0 = (unsigned short*)(lds + 16384);
        unsigned short* Bs1 = (unsigned short*)(lds + 24576);
        const int K = 1024;
        const int wr = wv >> 1, wc = wv & 1;
        const int sseg = ((lane & 3) ^ ((lane >> 3) & 3)) * 8;
        const int mrow = lane & 15;
        const int kqx  = (((lane >> 4) ^ ((lane >> 1) & 3))) * 8;
        const int wo = wv * 32 * 32;

        for (int j = 0; j < 2; ++j) {
            const int u = blk * 2 + j;          // tile 0..1023
            const int tM = (u >> 3) * 128;
            const int tN = (u & 7) * 128;
            f32x4 acc[4][4] = {};
            const unsigned short* Ag = ybuf + (size_t)(tM + wv * 32 + (lane >> 2)) * K + sseg;
            const unsigned short* Bg = wprojb + (size_t)(tN + wv * 32 + (lane >> 2)) * K + sseg;
            for (int k0 = 0; k0 < K; k0 += 64) {
                __syncthreads();
                async16(Ag + k0,               &As0[wo]);
                async16(Ag + k0 + 16 * K,      &As0[wo + 16 * 32]);
                async16(Ag + k0 + 32,          &As1[wo]);
                async16(Ag + k0 + 32 + 16 * K, &As1[wo + 16 * 32]);
                async16(Bg + k0,               &Bs0[wo]);
                async16(Bg + k0 + 16 * K,      &Bs0[wo + 16 * 32]);
                async16(Bg + k0 + 32,          &Bs1[wo]);
                async16(Bg + k0 + 32 + 16 * K, &Bs1[wo + 16 * 32]);
                asm volatile("s_waitcnt vmcnt(0)" ::: "memory");
                __syncthreads();
                s8v af[4], bf[4];
#pragma unroll
                for (int mi = 0; mi < 4; ++mi)
                    af[mi] = *(const s8v*)&As0[(wr * 64 + mi * 16 + mrow) * 32 + kqx];
#pragma unroll
                for (int ni = 0; ni < 4; ++ni)
                    bf[ni] = *(const s8v*)&Bs0[(wc * 64 + ni * 16 + mrow) * 32 + kqx];
#pragma unroll
                for (int mi = 0; mi < 4; ++mi)
#pragma unroll
                    for (int ni = 0; ni < 4; ++ni)
                        acc[mi][ni] = __builtin_amdgcn_mfma_f32_16x16x32_bf16(
                            af[mi], bf[ni], acc[mi][ni], 0, 0, 0);
#pragma unroll
                for (int mi = 0; mi < 4; ++mi)
                    af[mi] = *(const s8v*)&As1[(wr * 64 + mi * 16 + mrow) * 32 + kqx];
#pragma unroll
                for (int ni = 0; ni < 4; ++ni)
                    bf[ni] = *(const s8v*)&Bs1[(wc * 64 + ni * 16 + mrow) * 32 + kqx];
#pragma unroll
                for (int mi = 0; mi < 4; ++mi)
#pragma unroll
                    for (int ni = 0; ni < 4; ++ni)
                        acc[mi][ni] = __builtin_amdgcn_mfma_f32_16x16x32_bf16(
                            af[mi], bf[ni], acc[mi][ni], 0, 0, 0);
            }
            const int crow0 = (lane >> 4) * 4;
            const int ccol  = lane & 15;
#pragma unroll
            for (int mi = 0; mi < 4; ++mi)
#pragma unroll
                for (int ni = 0; ni < 4; ++ni) {
                    int row = tM + wr * 64 + mi * 16 + crow0;
                    int col = tN + wc * 64 + ni * 16 + ccol;
#pragma unroll
                    for (int r2 = 0; r2 < 4; ++r2)
                        out[(size_t)(row + r2) * 1024 + col] = acc[mi][ni][r2] + bias[col];
                }
            __syncthreads();
        }
    }
}

// ---------------------------------------------------------------------------
extern "C" void kernel_launch(void* const* d_in, const int* in_sizes, int n_in,
                              void* d_out, int out_size, void* d_ws, size_t ws_size,
                              hipStream_t stream) {
    const float* x     = (const float*)d_in[0];   // (4,4096,1024)
    const float* Wqkv  = (const float*)d_in[1];   // (3072,1024)
    const float* Wproj = (const float*)d_in[2];   // (1024,1024)
    const float* bproj = (const float*)d_in[3];   // (1024,)
    float* out = (float*)d_out;                   // (4,4096,1024) fp32

    const int M = 16384, Cdim = 1024, O1 = 3072;

    unsigned short* xb     = (unsigned short*)d_ws;
    unsigned short* wqkvb  = xb + (size_t)M * Cdim;
    unsigned short* wprojb = wqkvb + (size_t)O1 * Cdim;
    unsigned short* qb     = wprojb + (size_t)Cdim * Cdim;        // Q token-major
    unsigned short* kvT    = qb + (size_t)M * Cdim;               // [4][2048][4096]
    unsigned short* ybuf   = kvT + (size_t)4 * 2048 * 4096;
    float* vkws            = (float*)(ybuf + (size_t)M * Cdim);
    unsigned* cnt          = (unsigned*)(vkws + 135168);          // barrier ctr
    // ws use: ~176 MB

    const int PREP_GROUPS = (16777216 + 3145728 + 1048576 + 135168 + 16) / 8;
    prep<<<(PREP_GROUPS + 255) / 256, 256, 0, stream>>>(
        x, Wqkv, Wproj, xb, wqkvb, wprojb, vkws);

    gemm_qkv<<<(M / 128) * (O1 / 128), 256, 0, stream>>>(
        xb, wqkvb, qb, kvT, M, O1, Cdim);

    attn_tail<<<512, 256, 0, stream>>>(
        kvT, qb, ybuf, wprojb, bproj, out, vkws, cnt);
}

// Round 9
// 341.445 us; speedup vs baseline: 1.3633x; 1.3633x over previous
//
#include <hip/hip_runtime.h>

// ---------------------------------------------------------------------------
// LiteMLA: B=4, N=4096, C=1024, D=32, h=32 heads.
//   qkv = x @ W_qkv^T            (16384 x 3072, K=1024)   [relu on q,k cols]
//   per (b,h): vk[d,e] = sum_n Vpad[d,n]*reluK[e,n]   (33x32, reduce N=4096)
//              y[d,n]  = (sum_e vk[d,e]*reluQ[e,n]) / (sum_e vk[32,e]*reluQ[e,n] + eps)
//   out = y @ W_proj^T + b_proj  (16384 x 1024, K=1024)
// gemm_qkv stores Q token-major, K/V transposed (kvT[b][ch][n]).
// GEMM grid is XCD-aware (xcd = blk&7): each XCD owns a 16-M-tile stripe and
// sweeps 8-wide N-panels with tN fastest -> B-panel L2-hot, A streamed once.
// LDS uses XOR k-octet swizzle (bank-conflict-free, verified R7).
// ---------------------------------------------------------------------------

using us8   = __attribute__((ext_vector_type(8))) unsigned short;
using us4   = __attribute__((ext_vector_type(4))) unsigned short;
using s8v   = __attribute__((ext_vector_type(8))) short;
using f32x4 = __attribute__((ext_vector_type(4))) float;

__device__ __forceinline__ unsigned short f2bf(float f) {
    union { float f; unsigned int u; } c; c.f = f;
    unsigned int r = c.u + 0x7fffu + ((c.u >> 16) & 1u);   // RTN-even
    return (unsigned short)(r >> 16);
}
__device__ __forceinline__ float bf2f(unsigned short u) {
    union { unsigned int u; float f; } c; c.u = ((unsigned int)u) << 16;
    return c.f;
}

// async global->LDS, 16B per lane; LDS dest = wave-uniform base + lane*16
__device__ __forceinline__ void async16(const unsigned short* g, unsigned short* l) {
    __builtin_amdgcn_global_load_lds(
        (const __attribute__((address_space(1))) unsigned int*)g,
        (__attribute__((address_space(3))) unsigned int*)l, 16, 0, 0);
}

// ------------------ fused fp32->bf16 converts + vkws zero ------------------
__global__ __launch_bounds__(256)
void prep(const float* __restrict__ x, const float* __restrict__ wq,
          const float* __restrict__ wp, unsigned short* __restrict__ xb,
          unsigned short* __restrict__ wqb, unsigned short* __restrict__ wpb,
          float* __restrict__ vkws) {
    const int NX = 16777216 / 8, NQ = 3145728 / 8, NP = 1048576 / 8, NZ = 135168 / 8;
    int gid = blockIdx.x * 256 + threadIdx.x;
    const float* in; unsigned short* out; int i;
    if (gid < NX)                    { in = x;  out = xb;  i = gid * 8; }
    else if (gid < NX + NQ)          { in = wq; out = wqb; i = (gid - NX) * 8; }
    else if (gid < NX + NQ + NP)     { in = wp; out = wpb; i = (gid - NX - NQ) * 8; }
    else if (gid < NX + NQ + NP + NZ) {
        int z = (gid - NX - NQ - NP) * 8;
        f32x4 zero = {};
        *(f32x4*)(vkws + z) = zero; *(f32x4*)(vkws + z + 4) = zero;
        return;
    } else return;
    float4 a = *(const float4*)(in + i);
    float4 b = *(const float4*)(in + i + 4);
    us8 o;
    o[0] = f2bf(a.x); o[1] = f2bf(a.y); o[2] = f2bf(a.z); o[3] = f2bf(a.w);
    o[4] = f2bf(b.x); o[5] = f2bf(b.y); o[6] = f2bf(b.z); o[7] = f2bf(b.w);
    *(us8*)(out + i) = o;
}

// ----------------------------- bf16 NT GEMM core ---------------------------
// 128x128 tile, BK=64 (two 32-panels), 256 threads (4 waves).
// MODE 0: cols<1024 -> Q token-major bf16 (relu); cols>=1024 -> kvT.
// MODE 1: fp32 + bias.
template <int MODE>
__device__ __forceinline__
void gemm_core(const unsigned short* __restrict__ A,
               const unsigned short* __restrict__ Bt,
               void* __restrict__ C, unsigned short* __restrict__ kvT,
               const float* __restrict__ bias,
               int M, int N, int K, int tM, int tN) {
    __shared__ unsigned short As0[128 * 32], As1[128 * 32];
    __shared__ unsigned short Bs0[128 * 32], Bs1[128 * 32];

    const int tid  = threadIdx.x;
    const int lane = tid & 63;
    const int wv   = tid >> 6;
    const int wr   = wv >> 1, wc = wv & 1;

    f32x4 acc[4][4] = {};

    const int sseg = ((lane & 3) ^ ((lane >> 3) & 3)) * 8;
    const unsigned short* Ag = A + (size_t)(tM + wv * 32 + (lane >> 2)) * K + sseg;
    const unsigned short* Bg = Bt + (size_t)(tN + wv * 32 + (lane >> 2)) * K + sseg;
    const int wo = wv * 32 * 32;

    const int mrow = lane & 15;
    const int kqx  = (((lane >> 4) ^ ((lane >> 1) & 3))) * 8;

    for (int k0 = 0; k0 < K; k0 += 64) {
        __syncthreads();
        async16(Ag + k0,               &As0[wo]);
        async16(Ag + k0 + 16 * K,      &As0[wo + 16 * 32]);
        async16(Ag + k0 + 32,          &As1[wo]);
        async16(Ag + k0 + 32 + 16 * K, &As1[wo + 16 * 32]);
        async16(Bg + k0,               &Bs0[wo]);
        async16(Bg + k0 + 16 * K,      &Bs0[wo + 16 * 32]);
        async16(Bg + k0 + 32,          &Bs1[wo]);
        async16(Bg + k0 + 32 + 16 * K, &Bs1[wo + 16 * 32]);
        asm volatile("s_waitcnt vmcnt(0)" ::: "memory");
        __syncthreads();
        s8v af[4], bf[4];
#pragma unroll
        for (int mi = 0; mi < 4; ++mi)
            af[mi] = *(const s8v*)&As0[(wr * 64 + mi * 16 + mrow) * 32 + kqx];
#pragma unroll
        for (int ni = 0; ni < 4; ++ni)
            bf[ni] = *(const s8v*)&Bs0[(wc * 64 + ni * 16 + mrow) * 32 + kqx];
#pragma unroll
        for (int mi = 0; mi < 4; ++mi)
#pragma unroll
            for (int ni = 0; ni < 4; ++ni)
                acc[mi][ni] = __builtin_amdgcn_mfma_f32_16x16x32_bf16(
                    af[mi], bf[ni], acc[mi][ni], 0, 0, 0);
#pragma unroll
        for (int mi = 0; mi < 4; ++mi)
            af[mi] = *(const s8v*)&As1[(wr * 64 + mi * 16 + mrow) * 32 + kqx];
#pragma unroll
        for (int ni = 0; ni < 4; ++ni)
            bf[ni] = *(const s8v*)&Bs1[(wc * 64 + ni * 16 + mrow) * 32 + kqx];
#pragma unroll
        for (int mi = 0; mi < 4; ++mi)
#pragma unroll
            for (int ni = 0; ni < 4; ++ni)
                acc[mi][ni] = __builtin_amdgcn_mfma_f32_16x16x32_bf16(
                    af[mi], bf[ni], acc[mi][ni], 0, 0, 0);
    }

    const int crow0 = (lane >> 4) * 4;
    const int ccol  = lane & 15;
    if (MODE == 0 && tN >= 1024) {
        const int b2 = tM >> 12;
        const int nb0 = (tM & 4095) + wr * 64;
#pragma unroll
        for (int mi = 0; mi < 4; ++mi) {
            int nbase = nb0 + mi * 16 + crow0;
#pragma unroll
            for (int ni = 0; ni < 4; ++ni) {
                int col = tN + wc * 64 + ni * 16 + ccol;
                f32x4 v = acc[mi][ni];
                if (col < 2048) {
                    v[0] = fmaxf(v[0], 0.f); v[1] = fmaxf(v[1], 0.f);
                    v[2] = fmaxf(v[2], 0.f); v[3] = fmaxf(v[3], 0.f);
                }
                us4 o;
                o[0] = f2bf(v[0]); o[1] = f2bf(v[1]);
                o[2] = f2bf(v[2]); o[3] = f2bf(v[3]);
                *(us4*)&kvT[((size_t)b2 * 2048 + (col - 1024)) * 4096 + nbase] = o;
            }
        }
    } else {
#pragma unroll
        for (int mi = 0; mi < 4; ++mi)
#pragma unroll
            for (int ni = 0; ni < 4; ++ni) {
                int row = tM + wr * 64 + mi * 16 + crow0;
                int col = tN + wc * 64 + ni * 16 + ccol;
#pragma unroll
                for (int r2 = 0; r2 < 4; ++r2) {
                    float v = acc[mi][ni][r2];
                    if (MODE == 0) {
                        v = fmaxf(v, 0.f);   // Q region always relu'd
                        ((unsigned short*)C)[(size_t)(row + r2) * 1024 + col] = f2bf(v);
                    } else {
                        ((float*)C)[(size_t)(row + r2) * N + col] = v + bias[col];
                    }
                }
            }
    }
}

// XCD-aware tile mapping: xcd = blk&7 owns M-stripe [xcd*16, xcd*16+16) tiles;
// within XCD, N-panels of 8 swept with tN fastest (B-panel 2MB stays L2-hot).
__device__ __forceinline__ void xcd_map(int blk, int MT, int& tM, int& tN) {
    const int xcd = blk & 7;
    const int i   = blk >> 3;
    const int MTx = MT >> 3;            // M-tiles per XCD (16)
    const int ppan = MTx * 8;           // blocks per panel per XCD
    const int p   = i / ppan;
    const int i2  = i % ppan;
    tM = (xcd * MTx + (i2 >> 3)) * 128;
    tN = (p * 8 + (i2 & 7)) * 128;
}

__global__ __launch_bounds__(256)
void gemm_qkv(const unsigned short* __restrict__ A,
              const unsigned short* __restrict__ Bt,
              unsigned short* __restrict__ Cq, unsigned short* __restrict__ kvT,
              int M, int N, int K) {
    int tM, tN;
    xcd_map(blockIdx.x, M >> 7, tM, tN);
    gemm_core<0>(A, Bt, (void*)Cq, kvT, nullptr, M, N, K, tM, tN);
}

__global__ __launch_bounds__(256)
void gemm_proj(const unsigned short* __restrict__ A,
               const unsigned short* __restrict__ Bt,
               float* __restrict__ C, const float* __restrict__ bias,
               int M, int N, int K) {
    int tM, tN;
    xcd_map(blockIdx.x, M >> 7, tM, tN);
    gemm_core<1>(A, Bt, (void*)C, nullptr, bias, M, N, K, tM, tN);
}

// ---------------- vk = Vpad @ reluK^T via MFMA over kvT --------------------
__global__ __launch_bounds__(256)
void lite_vk(const unsigned short* __restrict__ kvT, float* __restrict__ vkws) {
    const int bh = blockIdx.x, ck = blockIdx.y;
    const int b = bh >> 5, h = bh & 31;
    const int S = 136;
    __shared__ unsigned short Ks[32 * S];
    __shared__ unsigned short Vs[32 * S];
    __shared__ float Rs[4][1088];
    const int t = threadIdx.x, lane = t & 63, wv = t >> 6;
    const unsigned short* Kp = kvT + ((size_t)b * 2048 + h * 32) * 4096 + ck * 512;
    const unsigned short* Vp = kvT + ((size_t)b * 2048 + 1024 + h * 32) * 4096 + ck * 512;
    const int sr = t >> 3, ss = (t & 7) * 16;
    f32x4 acc00 = {}, acc01 = {}, acc10 = {}, acc11 = {}, accO0 = {}, accO1 = {};
    s8v ones;
#pragma unroll
    for (int j = 0; j < 8; ++j) ones[j] = (short)0x3F80;
    const int mrow = lane & 15, kq = (lane >> 4) * 8;

    for (int tile = 0; tile < 4; ++tile) {
        int go = tile * 128 + ss;
        us8 k0v = *(const us8*)(Kp + (size_t)sr * 4096 + go);
        us8 k1v = *(const us8*)(Kp + (size_t)sr * 4096 + go + 8);
        us8 v0v = *(const us8*)(Vp + (size_t)sr * 4096 + go);
        us8 v1v = *(const us8*)(Vp + (size_t)sr * 4096 + go + 8);
        __syncthreads();
        *(us8*)&Ks[sr * S + ss]     = k0v;
        *(us8*)&Ks[sr * S + ss + 8] = k1v;
        *(us8*)&Vs[sr * S + ss]     = v0v;
        *(us8*)&Vs[sr * S + ss + 8] = v1v;
        __syncthreads();
        int ko = wv * 32 + kq;
        s8v a0 = *(const s8v*)&Vs[(mrow)      * S + ko];
        s8v a1 = *(const s8v*)&Vs[(16 + mrow) * S + ko];
        s8v b0 = *(const s8v*)&Ks[(mrow)      * S + ko];
        s8v b1 = *(const s8v*)&Ks[(16 + mrow) * S + ko];
        acc00 = __builtin_amdgcn_mfma_f32_16x16x32_bf16(a0, b0, acc00, 0, 0, 0);
        acc01 = __builtin_amdgcn_mfma_f32_16x16x32_bf16(a0, b1, acc01, 0, 0, 0);
        acc10 = __builtin_amdgcn_mfma_f32_16x16x32_bf16(a1, b0, acc10, 0, 0, 0);
        acc11 = __builtin_amdgcn_mfma_f32_16x16x32_bf16(a1, b1, acc11, 0, 0, 0);
        accO0 = __builtin_amdgcn_mfma_f32_16x16x32_bf16(ones, b0, accO0, 0, 0, 0);
        accO1 = __builtin_amdgcn_mfma_f32_16x16x32_bf16(ones, b1, accO1, 0, 0, 0);
    }

    const int ccol = lane & 15, crow = (lane >> 4) * 4;
    float* R = Rs[wv];
#pragma unroll
    for (int r2 = 0; r2 < 4; ++r2) {
        R[(crow + r2) * 32 + ccol]           = acc00[r2];
        R[(crow + r2) * 32 + 16 + ccol]      = acc01[r2];
        R[(16 + crow + r2) * 32 + ccol]      = acc10[r2];
        R[(16 + crow + r2) * 32 + 16 + ccol] = acc11[r2];
    }
    if ((lane >> 4) == 0) {
        R[1024 + ccol]      = accO0[0];
        R[1024 + 16 + ccol] = accO1[0];
    }
    __syncthreads();
    float* vkb = vkws + bh * (33 * 32);
    for (int i = t; i < 1056; i += 256) {
        float s = Rs[0][i] + Rs[1][i] + Rs[2][i] + Rs[3][i];
        atomicAdd(&vkb[i], s);
    }
}

// --------------- y = (vk @ reluQ) / pad-row, MFMA K=32 ---------------------
__global__ __launch_bounds__(256)
void lite_apply(const unsigned short* __restrict__ qb,
                const float* __restrict__ vkws,
                unsigned short* __restrict__ yb) {
    const int bh = blockIdx.x, nb = blockIdx.y;
    const int b = bh >> 5, h = bh & 31;
    __shared__ unsigned short vkh[48 * 32];
    __shared__ unsigned short vkl[48 * 32];
    const int t = threadIdx.x;
    for (int i = t; i < 48 * 32; i += 256) {
        float v = (i < 33 * 32) ? vkws[bh * (33 * 32) + i] : 0.f;
        unsigned short hi = f2bf(v);
        vkh[i] = hi;
        vkl[i] = f2bf(v - bf2f(hi));
    }
    __syncthreads();

    const int lane = t & 63, wv = t >> 6;
    const int col = lane & 15, quad = lane >> 4;
    s8v b0h = *(const s8v*)&vkh[(col)      * 32 + quad * 8];
    s8v b0l = *(const s8v*)&vkl[(col)      * 32 + quad * 8];
    s8v b1h = *(const s8v*)&vkh[(16 + col) * 32 + quad * 8];
    s8v b1l = *(const s8v*)&vkl[(16 + col) * 32 + quad * 8];
    s8v b2h = *(const s8v*)&vkh[(32 + col) * 32 + quad * 8];
    s8v b2l = *(const s8v*)&vkl[(32 + col) * 32 + quad * 8];

    const int ntile = nb * 256 + wv * 64;
#pragma unroll
    for (int mi = 0; mi < 4; ++mi) {
        int tok = ntile + mi * 16 + col;
        const unsigned short* qp =
            qb + (size_t)(b * 4096 + tok) * 1024 + h * 32 + quad * 8;
        s8v a = *(const s8v*)qp;
        f32x4 n0 = {}, n1 = {}, dd = {};
        n0 = __builtin_amdgcn_mfma_f32_16x16x32_bf16(b0h, a, n0, 0, 0, 0);
        n0 = __builtin_amdgcn_mfma_f32_16x16x32_bf16(b0l, a, n0, 0, 0, 0);
        n1 = __builtin_amdgcn_mfma_f32_16x16x32_bf16(b1h, a, n1, 0, 0, 0);
        n1 = __builtin_amdgcn_mfma_f32_16x16x32_bf16(b1l, a, n1, 0, 0, 0);
        dd = __builtin_amdgcn_mfma_f32_16x16x32_bf16(b2h, a, dd, 0, 0, 0);
        dd = __builtin_amdgcn_mfma_f32_16x16x32_bf16(b2l, a, dd, 0, 0, 0);
        float den  = __shfl(dd[0], col, 64);
        float rinv = 1.f / (den + 1e-15f);
        us4 o0, o1;
#pragma unroll
        for (int r = 0; r < 4; ++r) {
            o0[r] = f2bf(n0[r] * rinv);
            o1[r] = f2bf(n1[r] * rinv);
        }
        size_t o = (size_t)(b * 4096 + tok) * 1024 + h * 32;
        *(us4*)&yb[o + quad * 4]      = o0;
        *(us4*)&yb[o + 16 + quad * 4] = o1;
    }
}

// ---------------------------------------------------------------------------
extern "C" void kernel_launch(void* const* d_in, const int* in_sizes, int n_in,
                              void* d_out, int out_size, void* d_ws, size_t ws_size,
                              hipStream_t stream) {
    const float* x     = (const float*)d_in[0];   // (4,4096,1024)
    const float* Wqkv  = (const float*)d_in[1];   // (3072,1024)
    const float* Wproj = (const float*)d_in[2];   // (1024,1024)
    const float* bproj = (const float*)d_in[3];   // (1024,)
    float* out = (float*)d_out;                   // (4,4096,1024) fp32

    const int M = 16384, Cdim = 1024, O1 = 3072;

    unsigned short* xb     = (unsigned short*)d_ws;
    unsigned short* wqkvb  = xb + (size_t)M * Cdim;
    unsigned short* wprojb = wqkvb + (size_t)O1 * Cdim;
    unsigned short* qb     = wprojb + (size_t)Cdim * Cdim;        // Q token-major
    unsigned short* kvT    = qb + (size_t)M * Cdim;               // [4][2048][4096]
    unsigned short* ybuf   = kvT + (size_t)4 * 2048 * 4096;
    float* vkws            = (float*)(ybuf + (size_t)M * Cdim);
    // ws use: ~176 MB

    const int PREP_GROUPS = (16777216 + 3145728 + 1048576 + 135168) / 8;
    prep<<<(PREP_GROUPS + 255) / 256, 256, 0, stream>>>(
        x, Wqkv, Wproj, xb, wqkvb, wprojb, vkws);

    gemm_qkv<<<(M / 128) * (O1 / 128), 256, 0, stream>>>(
        xb, wqkvb, qb, kvT, M, O1, Cdim);

    lite_vk<<<dim3(128, 8), 256, 0, stream>>>(kvT, vkws);
    lite_apply<<<dim3(128, 16), 256, 0, stream>>>(qb, vkws, ybuf);

    gemm_proj<<<(M / 128) * (Cdim / 128), 256, 0, stream>>>(
        ybuf, wprojb, out, bproj, M, Cdim, Cdim);
}